// Round 20
// baseline (745.717 us; speedup 1.0000x reference)
//
#include <hip/hip_runtime.h>
#include <math.h>

#define NTOK 65536   // B*T = 8*8192
#define T_   8192
#define C_   512

typedef short short8 __attribute__((ext_vector_type(8)));
typedef float f32x4  __attribute__((ext_vector_type(4)));

#define GLDS(gp, lp) __builtin_amdgcn_global_load_lds( \
    (__attribute__((address_space(1))) void*)(void*)(gp), \
    (__attribute__((address_space(3))) void*)(lp), 16, 0, 0)

__device__ __forceinline__ unsigned short f2bf(float f){
  unsigned x = __float_as_uint(f);
  x += 0x7fffu + ((x >> 16) & 1u);
  return (unsigned short)(x >> 16);
}
__device__ __forceinline__ float bflo(unsigned p){ return __uint_as_float(p << 16); }
__device__ __forceinline__ float bfhi(unsigned p){ return __uint_as_float(p & 0xffff0000u); }
__device__ __forceinline__ float bfs(unsigned short u){ return __uint_as_float(((unsigned)u) << 16); }
__device__ __forceinline__ unsigned pack2(float a, float b){
  return (unsigned)f2bf(a) | ((unsigned)f2bf(b) << 16);
}
// bijective XCD chunking (m204)
__device__ __forceinline__ int xcd_remap(int flat, int nwg){
  int q = nwg >> 3, r = nwg & 7;
  int xcd = flat & 7, idx = flat >> 3;
  return (xcd < r ? xcd * (q + 1) : r * (q + 1) + (xcd - r) * q) + idx;
}

// ---------------- fused weight prep: 1 kernel, block-range dispatch ----------------
__global__ __launch_bounds__(256) void k_prep(const float* __restrict__ mb,
                                              const float* __restrict__ gate_w,
                                              const float* __restrict__ w1,
                                              const float* __restrict__ w2,
                                              unsigned short* __restrict__ mb_bf,
                                              unsigned short* __restrict__ mbT,
                                              unsigned short* __restrict__ gwT,
                                              unsigned short* __restrict__ w1T,
                                              unsigned short* __restrict__ w2T){
  __shared__ float tile[64][65];
  const int bid = blockIdx.x;
  const float* src; unsigned short* dst; int R, S, t0;
  if (bid < 64)       { src = mb;     dst = mbT; R = 512;  S = 512;  t0 = bid; }
  else if (bid < 192) { src = gate_w; dst = gwT; R = 512;  S = 1024; t0 = bid - 64; }
  else if (bid < 448) { src = w1;     dst = w1T; R = 512;  S = 2048; t0 = bid - 192; }
  else if (bid < 704) { src = w2;     dst = w2T; R = 2048; S = 512;  t0 = bid - 448; }
  else {
    int i = (bid - 704) * 256 + threadIdx.x;
    mb_bf[i] = f2bf(mb[i]);
    return;
  }
  int ntS = S >> 6;
  int tr = t0 / ntS, ts = t0 - tr * ntS;
  int tx = threadIdx.x & 63, tg = threadIdx.x >> 6;
  #pragma unroll
  for (int rr = tg; rr < 64; rr += 4)
    tile[rr][tx] = src[(size_t)(tr * 64 + rr) * S + ts * 64 + tx];
  __syncthreads();
  #pragma unroll
  for (int rr = tg; rr < 64; rr += 4)
    dst[(size_t)(ts * 64 + rr) * R + tr * 64 + tx] = f2bf(tile[tx][rr]);
}

// -------- layernorm (f32 in): one row per WAVE; also emits (mu, sigma) per row --------
__global__ __launch_bounds__(256) void k_ln4(const float* __restrict__ x,
                                             const float* __restrict__ g,
                                             const float* __restrict__ b,
                                             unsigned* __restrict__ outbf,
                                             float* __restrict__ rowstat){
  const int row  = blockIdx.x * 4 + (threadIdx.x >> 6);
  const int lane = threadIdx.x & 63;
  const float4* xr = (const float4*)(x + (size_t)row * C_) + lane * 2;
  float4 v0 = xr[0], v1 = xr[1];
  float s  = v0.x + v0.y + v0.z + v0.w + v1.x + v1.y + v1.z + v1.w;
  float ss = v0.x*v0.x + v0.y*v0.y + v0.z*v0.z + v0.w*v0.w
           + v1.x*v1.x + v1.y*v1.y + v1.z*v1.z + v1.w*v1.w;
  #pragma unroll
  for (int o = 32; o; o >>= 1){ s += __shfl_xor(s, o); ss += __shfl_xor(ss, o); }
  float mu  = s * (1.0f / C_);
  float var = ss * (1.0f / C_) - mu * mu;
  float rs = rsqrtf(var + 1e-5f);
  if (lane == 0){ rowstat[2*row] = mu; rowstat[2*row+1] = 1.0f / rs; }
  const float4* gr = (const float4*)g + lane * 2;
  const float4* br = (const float4*)b + lane * 2;
  float4 g0 = gr[0], g1 = gr[1], b0 = br[0], b1 = br[1];
  uint4 o4;
  o4.x = pack2((v0.x - mu) * rs * g0.x + b0.x, (v0.y - mu) * rs * g0.y + b0.y);
  o4.y = pack2((v0.z - mu) * rs * g0.z + b0.z, (v0.w - mu) * rs * g0.w + b0.w);
  o4.z = pack2((v1.x - mu) * rs * g1.x + b1.x, (v1.y - mu) * rs * g1.y + b1.y);
  o4.w = pack2((v1.z - mu) * rs * g1.z + b1.z, (v1.w - mu) * rs * g1.w + b1.w);
  ((uint4*)(outbf + (size_t)row * 256))[lane] = o4;
}

// -------- layernorm (bf16 in): one row per WAVE, shuffle-only reduce --------
__global__ __launch_bounds__(256) void k_ln4b(const unsigned* __restrict__ xb,
                                              const float* __restrict__ g,
                                              const float* __restrict__ b,
                                              unsigned* __restrict__ outbf){
  const int row  = blockIdx.x * 4 + (threadIdx.x >> 6);
  const int lane = threadIdx.x & 63;
  uint4 p = ((const uint4*)(xb + (size_t)row * 256))[lane];
  float v[8];
  v[0]=bflo(p.x); v[1]=bfhi(p.x); v[2]=bflo(p.y); v[3]=bfhi(p.y);
  v[4]=bflo(p.z); v[5]=bfhi(p.z); v[6]=bflo(p.w); v[7]=bfhi(p.w);
  float s = 0.f, ss = 0.f;
  #pragma unroll
  for (int k = 0; k < 8; k++){ s += v[k]; ss += v[k]*v[k]; }
  #pragma unroll
  for (int o = 32; o; o >>= 1){ s += __shfl_xor(s, o); ss += __shfl_xor(ss, o); }
  float mu  = s * (1.0f / C_);
  float var = ss * (1.0f / C_) - mu * mu;
  float rs = rsqrtf(var + 1e-5f);
  const float4* gr = (const float4*)g + lane * 2;
  const float4* br = (const float4*)b + lane * 2;
  float4 g0 = gr[0], g1 = gr[1], b0 = br[0], b1 = br[1];
  uint4 o4;
  o4.x = pack2((v[0] - mu) * rs * g0.x + b0.x, (v[1] - mu) * rs * g0.y + b0.y);
  o4.y = pack2((v[2] - mu) * rs * g0.z + b0.z, (v[3] - mu) * rs * g0.w + b0.w);
  o4.z = pack2((v[4] - mu) * rs * g1.x + b1.x, (v[5] - mu) * rs * g1.y + b1.y);
  o4.w = pack2((v[6] - mu) * rs * g1.z + b1.z, (v[7] - mu) * rs * g1.w + b1.w);
  ((uint4*)(outbf + (size_t)row * 256))[lane] = o4;
}

// ---- depthwise causal conv K=3: 8 consecutive tokens per thread ----
__global__ __launch_bounds__(256) void k_conv8(const unsigned* __restrict__ xn,
                                               const float* __restrict__ w,
                                               const float* __restrict__ bias,
                                               unsigned* __restrict__ loc,
                                               int base){
  const int cp = threadIdx.x;
  const size_t n0 = (size_t)blockIdx.x * 8 + (size_t)base;
  const int t0 = (int)(n0 & (T_ - 1));
  const int c = cp * 2;
  const float w00 = w[c*3], w01 = w[c*3+1], w02 = w[c*3+2];
  const float w10 = w[c*3+3], w11 = w[c*3+4], w12 = w[c*3+5];
  const float b0 = bias[c], b1 = bias[c+1];
  unsigned vm2 = (t0 >= 2) ? xn[(n0 - 2) * 256 + cp] : 0u;
  unsigned vm1 = (t0 >= 1) ? xn[(n0 - 1) * 256 + cp] : 0u;
  size_t obase = (n0 - (size_t)base) * 256 + cp;
  #pragma unroll
  for (int k = 0; k < 8; k++){
    unsigned v = xn[(n0 + k) * 256 + cp];
    float r0 = b0 + bflo(v)*w02 + bflo(vm1)*w01 + bflo(vm2)*w00;
    float r1 = b1 + bfhi(v)*w12 + bfhi(vm1)*w11 + bfhi(vm2)*w10;
    loc[obase + (size_t)k * 256] = pack2(r0, r1);
    vm2 = vm1; vm1 = v;
  }
}

// ---- row sum of exp'd scores (bf16): zinv[row] = 1/sum, one row per wave ----
__global__ __launch_bounds__(256) void k_rowsum(const unsigned* __restrict__ e,
                                                float* __restrict__ zinv){
  const int row  = blockIdx.x * 4 + (threadIdx.x >> 6);
  const int lane = threadIdx.x & 63;
  uint4 p = ((const uint4*)(e + (size_t)row * 256))[lane];
  float s = bflo(p.x)+bfhi(p.x)+bflo(p.y)+bfhi(p.y)
          + bflo(p.z)+bfhi(p.z)+bflo(p.w)+bfhi(p.w);
  #pragma unroll
  for (int o = 32; o; o >>= 1) s += __shfl_xor(s, o);
  if (lane == 0) zinv[row] = 1.0f / s;
}

// =================== 256x256 8-phase bf16 GEMM (T1+T2+T3+T4+T5) ===================
// EPI: 1=bf16, 2=exp(acc)->bf16, 3=gelu(acc+bias)->bf16 (tanh-form),
//      4=acc+bias+f32 add->f32, 5=acc+bias+bf16 add->f32, 7=acc*bias[row]->bf16
// bf16-out EPIs use an LDS-staged COALESCED epilogue: C tile (256x256 bf16 =
// 128KB) is written to the (dead) LDS, then copied out row-linear in uint4.
#define PH_PRE  { __builtin_amdgcn_s_barrier(); \
                  asm volatile("s_waitcnt lgkmcnt(0)" ::: "memory"); \
                  __builtin_amdgcn_sched_barrier(0); }
#define PH_END  __builtin_amdgcn_s_barrier();
#define VMW2    asm volatile("s_waitcnt vmcnt(2)" ::: "memory");
#define VMW0    asm volatile("s_waitcnt vmcnt(0)" ::: "memory");

template<int EPI, int K, int N>
__global__ __launch_bounds__(512, 2) void k_g256(const unsigned short* __restrict__ A,
                                                 const unsigned short* __restrict__ Bt,
                                                 void* __restrict__ out,
                                                 const float* __restrict__ bias,
                                                 const void* __restrict__ add){
  __shared__ char smem[131072];
  const int tid  = threadIdx.x;
  const int lane = tid & 63;
  const int w    = tid >> 6;
  const int wr   = w >> 2, wc = w & 3;
  const int nwg  = gridDim.x * gridDim.y;
  const int wgid = xcd_remap(blockIdx.y * gridDim.x + blockIdx.x, nwg);
  const long bcol = (long)(wgid % gridDim.x) * 256;
  const long brow = (long)(wgid / gridDim.x) * 256;
  const int lr = lane & 15;
  const int lk = (lane >> 4) * 16;
  const int srow  = tid >> 3;
  const int sbyte = ((tid & 7) * 16) ^ ((srow & 7) << 4);   // T2 pre-swizzled source col
  const unsigned swb = (unsigned)(w * 1024);
  const int rsw = (lr & 7) << 4;                            // T2 read-side XOR

  f32x4 acc[8][4];
  #pragma unroll
  for (int i = 0; i < 8; i++)
    #pragma unroll
    for (int j = 0; j < 4; j++){ f32x4 z = {0.f,0.f,0.f,0.f}; acc[i][j] = z; }

  const char* Ab = (const char*)(A + brow * (long)K);
  const char* Bb = (const char*)(Bt + bcol * (long)K);

  auto ST = [&](const char* g, int ldsoff, int row0, int kt){
    GLDS(g + ((long)(row0 + srow) * K + (long)kt * 64) * 2 + sbyte,
         smem + ldsoff + row0 * 128 + swb);
  };
  auto stA0 = [&](int b, int kt){ ST(Ab, b*32768, 0,  kt); ST(Ab, b*32768, 128, kt); };
  auto stA1 = [&](int b, int kt){ ST(Ab, b*32768, 64, kt); ST(Ab, b*32768, 192, kt); };
  auto stB0 = [&](int b, int kt){ ST(Bb, 65536+b*32768, 0,   kt); ST(Bb, 65536+b*32768, 64,  kt); };
  auto stB1 = [&](int b, int kt){ ST(Bb, 65536+b*32768, 128, kt); ST(Bb, 65536+b*32768, 192, kt); };

  short8 afr[4][2], bfr[2][2];
  auto RDA = [&](int b, int qm){
    #pragma unroll
    for (int mj = 0; mj < 4; mj++)
      #pragma unroll
      for (int kk = 0; kk < 2; kk++)
        afr[mj][kk] = *(const short8*)(smem + b*32768 +
            (wr*128 + (qm*4+mj)*16 + lr) * 128 + ((kk*64 + lk) ^ rsw));
  };
  auto RDB = [&](int b, int qn){
    #pragma unroll
    for (int nj = 0; nj < 2; nj++)
      #pragma unroll
      for (int kk = 0; kk < 2; kk++)
        bfr[nj][kk] = *(const short8*)(smem + 65536 + b*32768 +
            (wc*64 + (qn*2+nj)*16 + lr) * 128 + ((kk*64 + lk) ^ rsw));
  };
  auto MM = [&](int qm, int qn){
    __builtin_amdgcn_s_setprio(1);
    #pragma unroll
    for (int mj = 0; mj < 4; mj++)
      #pragma unroll
      for (int nj = 0; nj < 2; nj++)
        #pragma unroll
        for (int kk = 0; kk < 2; kk++)
          acc[qm*4+mj][qn*2+nj] =
            __builtin_amdgcn_mfma_f32_16x16x32_bf16(afr[mj][kk], bfr[nj][kk],
                                                    acc[qm*4+mj][qn*2+nj], 0, 0, 0);
    __builtin_amdgcn_s_setprio(0);
  };

  constexpr int nt    = K >> 6;
  constexpr int niter = nt >> 1;

  stA0(0, 0); stA1(0, 0); stB0(0, 0); stB1(0, 0);
  stA0(1, 1);
  VMW2;
  __builtin_amdgcn_s_barrier();

  #pragma unroll 1
  for (int i = 0; i < niter; i++){
    const int t = 2 * i;
    RDA(0,0); RDB(0,0); stA1(1, t+1);
    PH_PRE; MM(0,0); PH_END;
    RDA(0,1); stB0(1, t+1);
    PH_PRE; MM(1,0); PH_END;
    RDA(0,0); RDB(0,1); stB1(1, t+1);
    PH_PRE; MM(0,1); PH_END;
    RDA(0,1); if (t + 2 < nt) stA0(0, t+2);
    PH_PRE; MM(1,1);
    if (t + 2 < nt) { VMW2; } else { VMW0; }
    PH_END;
    RDA(1,0); RDB(1,0); if (t + 2 < nt) stA1(0, t+2);
    PH_PRE; MM(0,0); PH_END;
    RDA(1,1); if (t + 2 < nt) stB0(0, t+2);
    PH_PRE; MM(1,0); PH_END;
    RDA(1,0); RDB(1,1); if (t + 2 < nt) stB1(0, t+2);
    PH_PRE; MM(0,1); PH_END;
    RDA(1,1); if (t + 3 < nt) stA0(1, t+3);
    PH_PRE; MM(1,1);
    if (i + 1 < niter){ if (t + 3 < nt) { VMW2; } else { VMW0; } }
    PH_END;
  }

  const long rb = brow + wr * 128;
  const long cb = bcol + wc * 64;
  if (EPI == 4 || EPI == 5){
    // f32 outputs: scattered store path (tile wouldn't fit LDS)
    #pragma unroll
    for (int mi = 0; mi < 8; mi++){
      #pragma unroll
      for (int ni = 0; ni < 4; ni++){
        long rg0 = rb + mi * 16 + (lane >> 4) * 4;
        long cg  = cb + ni * 16 + lr;
        #pragma unroll
        for (int j = 0; j < 4; j++){
          long oi = (rg0 + j) * (long)N + cg;
          float v = acc[mi][ni][j];
          if (EPI == 4) v += bias[cg] + ((const float*)add)[oi];
          else          v += bias[cg] + bfs(((const unsigned short*)add)[oi]);
          ((float*)out)[oi] = v;
        }
      }
    }
  } else {
    // bf16 outputs: LDS-staged coalesced epilogue (LDS is dead after final PH_END)
    unsigned short* lc = (unsigned short*)smem;
    const int rl0 = wr * 128;
    const int cl0 = wc * 64;
    #pragma unroll
    for (int mi = 0; mi < 8; mi++){
      #pragma unroll
      for (int ni = 0; ni < 4; ni++){
        int rl = rl0 + mi * 16 + (lane >> 4) * 4;
        int cl = cl0 + ni * 16 + lr;
        #pragma unroll
        for (int j = 0; j < 4; j++){
          float v = acc[mi][ni][j];
          unsigned short us;
          if (EPI == 1){
            us = f2bf(v);
          } else if (EPI == 2){
            us = f2bf(__expf(v));
          } else if (EPI == 3){
            v += bias[bcol + cl];
            float u = v * (1.5957691216f + 0.0713548162f * v * v);
            us = f2bf(v / (1.0f + __expf(-u)));
          } else {   // EPI == 7
            us = f2bf(v * bias[rb + mi * 16 + (lane >> 4) * 4 + j]);
          }
          lc[(rl + j) * 256 + cl] = us;
        }
      }
    }
    __syncthreads();
    unsigned short* ob = (unsigned short*)out + brow * (long)N + bcol;
    #pragma unroll
    for (int k2 = 0; k2 < 16; k2++){
      int idx = tid + (k2 << 9);     // 0..8191
      int r  = idx >> 5;             // row 0..255
      int cq = idx & 31;             // uint4 index within row
      *(uint4*)(ob + (long)r * N + cq * 8) = *(const uint4*)(lc + r * 256 + cq * 8);
    }
  }
}

// ===== fused gates GEMM (8-phase) + sigmoid + gated combine + residual =====
// X2BF: 0 -> write x2 f32, 1 -> write x2 bf16
// x is NOT read: reconstructed from the L2-hot xn panel (A) via per-row (mu,sigma).
template<int X2BF>
__global__ __launch_bounds__(512, 2) void k_gc256(const unsigned short* __restrict__ A,
                                                  const unsigned short* __restrict__ Bt,
                                                  const float* __restrict__ gb,
                                                  const unsigned short* __restrict__ loc,
                                                  const unsigned short* __restrict__ ctx,
                                                  const float* __restrict__ rowstat,
                                                  const float* __restrict__ l1g,
                                                  const float* __restrict__ l1b,
                                                  void* __restrict__ x2v){
  __shared__ char smem[131072];
  const int tid  = threadIdx.x;
  const int lane = tid & 63;
  const int w    = tid >> 6;
  const int wr   = w >> 2, wc = w & 3;
  const int nwg  = gridDim.x * gridDim.y;
  const int wgid = xcd_remap(blockIdx.y * gridDim.x + blockIdx.x, nwg);
  const int  bcol = (wgid % gridDim.x) * 128;
  const long brow = (long)(wgid / gridDim.x) * 256;
  const int K = 512;
  const int lr = lane & 15;
  const int lk = (lane >> 4) * 16;
  const int srow  = tid >> 3;
  const int sbyte = ((tid & 7) * 16) ^ ((srow & 7) << 4);
  const unsigned swb = (unsigned)(w * 1024);
  const int rsw = (lr & 7) << 4;

  f32x4 acc[8][2][2];
  #pragma unroll
  for (int i = 0; i < 8; i++)
    #pragma unroll
    for (int j = 0; j < 2; j++)
      #pragma unroll
      for (int h = 0; h < 2; h++){ f32x4 z = {0.f,0.f,0.f,0.f}; acc[i][j][h] = z; }

  const char* Ab  = (const char*)(A + brow * (long)K);
  const char* BbL = (const char*)(Bt + (long)bcol * K);
  const char* BbG = (const char*)(Bt + (long)(512 + bcol) * K);

  auto ST = [&](const char* g, int ldsoff, int row0, int kt){
    GLDS(g + ((long)(row0 + srow) * K + (long)kt * 64) * 2 + sbyte,
         smem + ldsoff + row0 * 128 + swb);
  };
  auto stA0 = [&](int b, int kt){ ST(Ab, b*32768, 0,  kt); ST(Ab, b*32768, 128, kt); };
  auto stA1 = [&](int b, int kt){ ST(Ab, b*32768, 64, kt); ST(Ab, b*32768, 192, kt); };
  auto stBL = [&](int b, int kt){ ST(BbL, 65536+b*32768,       0, kt); ST(BbL, 65536+b*32768,       64, kt); };
  auto stBG = [&](int b, int kt){ ST(BbG, 65536+b*32768+16384, 0, kt); ST(BbG, 65536+b*32768+16384, 64, kt); };

  short8 afr[4][2], bfr[2][2];
  auto RDA = [&](int b, int qm){
    #pragma unroll
    for (int mj = 0; mj < 4; mj++)
      #pragma unroll
      for (int kk = 0; kk < 2; kk++)
        afr[mj][kk] = *(const short8*)(smem + b*32768 +
            (wr*128 + (qm*4+mj)*16 + lr) * 128 + ((kk*64 + lk) ^ rsw));
  };
  auto RDB = [&](int b, int h){
    #pragma unroll
    for (int nj = 0; nj < 2; nj++)
      #pragma unroll
      for (int kk = 0; kk < 2; kk++)
        bfr[nj][kk] = *(const short8*)(smem + 65536 + b*32768 + h*16384 +
            (wc*32 + nj*16 + lr) * 128 + ((kk*64 + lk) ^ rsw));
  };
  auto MM = [&](int qm, int h){
    __builtin_amdgcn_s_setprio(1);
    #pragma unroll
    for (int mj = 0; mj < 4; mj++)
      #pragma unroll
      for (int nj = 0; nj < 2; nj++)
        #pragma unroll
        for (int kk = 0; kk < 2; kk++)
          acc[qm*4+mj][nj][h] =
            __builtin_amdgcn_mfma_f32_16x16x32_bf16(afr[mj][kk], bfr[nj][kk],
                                                    acc[qm*4+mj][nj][h], 0, 0, 0);
    __builtin_amdgcn_s_setprio(0);
  };

  constexpr int nt = 8, niter = 4;   // K=512

  stA0(0, 0); stA1(0, 0); stBL(0, 0); stBG(0, 0);
  stA0(1, 1);
  VMW2;
  __builtin_amdgcn_s_barrier();

  #pragma unroll 1
  for (int i = 0; i < niter; i++){
    const int t = 2 * i;
    RDA(0,0); RDB(0,0); stA1(1, t+1);
    PH_PRE; MM(0,0); PH_END;
    RDA(0,1); stBL(1, t+1);
    PH_PRE; MM(1,0); PH_END;
    RDA(0,0); RDB(0,1); stBG(1, t+1);
    PH_PRE; MM(0,1); PH_END;
    RDA(0,1); if (t + 2 < nt) stA0(0, t+2);
    PH_PRE; MM(1,1);
    if (t + 2 < nt) { VMW2; } else { VMW0; }
    PH_END;
    RDA(1,0); RDB(1,0); if (t + 2 < nt) stA1(0, t+2);
    PH_PRE; MM(0,0); PH_END;
    RDA(1,1); if (t + 2 < nt) stBL(0, t+2);
    PH_PRE; MM(1,0); PH_END;
    RDA(1,0); RDB(1,1); if (t + 2 < nt) stBG(0, t+2);
    PH_PRE; MM(0,1); PH_END;
    RDA(1,1); if (t + 3 < nt) stA0(1, t+3);
    PH_PRE; MM(1,1);
    if (i + 1 < niter){ if (t + 3 < nt) { VMW2; } else { VMW0; } }
    PH_END;
  }

  const long rbase = brow + wr * 128;
  const int  cb_   = bcol + wc * 32;
  // pass 1: issue xn re-reads (L2-hot: this block just streamed its A-panel)
  unsigned short xnp[8][2][4];
  #pragma unroll
  for (int mi = 0; mi < 8; mi++){
    #pragma unroll
    for (int ni = 0; ni < 2; ni++){
      long rg0 = rbase + mi * 16 + (lane >> 4) * 4;
      int  cg  = cb_ + ni * 16 + lr;
      #pragma unroll
      for (int j = 0; j < 4; j++)
        xnp[mi][ni][j] = A[(rg0 + j) * 512 + cg];
    }
  }
  // pass 2: reconstruct x, sigmoid-combine, store
  #pragma unroll
  for (int mi = 0; mi < 8; mi++){
    #pragma unroll
    for (int ni = 0; ni < 2; ni++){
      long rg0 = rbase + mi * 16 + (lane >> 4) * 4;
      int  cg  = cb_ + ni * 16 + lr;
      float bL = gb[cg], bG = gb[512 + cg];
      float lg = l1g[cg], lb = l1b[cg];
      float ig = 1.0f / lg;
      #pragma unroll
      for (int j = 0; j < 4; j++){
        long rg = rg0 + j;
        long oi = rg * 512 + cg;
        float mu = rowstat[2*rg], sg = rowstat[2*rg+1];
        float xv = (bfs(xnp[mi][ni][j]) - lb) * ig * sg + mu;
        float vL = 1.0f / (1.0f + __expf(-(acc[mi][ni][0][j] + bL)));
        float vG = 1.0f / (1.0f + __expf(-(acc[mi][ni][1][j] + bG)));
        float r = xv + vL * bfs(loc[oi]) + vG * bfs(ctx[oi]);
        if (X2BF) ((unsigned short*)x2v)[oi] = f2bf(r);
        else      ((float*)x2v)[oi] = r;
      }
    }
  }
}

// ---------------- launch ----------------
extern "C" void kernel_launch(void* const* d_in, const int* in_sizes, int n_in,
                              void* d_out, int out_size, void* d_ws, size_t ws_size,
                              hipStream_t stream){
  const float* x      = (const float*)d_in[0];
  const float* conv_w = (const float*)d_in[1];
  const float* conv_b = (const float*)d_in[2];
  const float* mb     = (const float*)d_in[3];
  const float* gate_w = (const float*)d_in[4];
  const float* gate_b = (const float*)d_in[5];
  const float* w1     = (const float*)d_in[6];
  const float* b1     = (const float*)d_in[7];
  const float* w2     = (const float*)d_in[8];
  const float* b2     = (const float*)d_in[9];
  const float* ln1g   = (const float*)d_in[10];
  const float* ln1b   = (const float*)d_in[11];
  const float* ln2g   = (const float*)d_in[12];
  const float* ln2b   = (const float*)d_in[13];

  char* ws = (char*)d_ws;
  const size_t MB = 1024ull * 1024ull;
  unsigned short* mb_bf = (unsigned short*)(ws + 0);
  unsigned short* mbT   = (unsigned short*)(ws + 512 * 1024);
  unsigned short* gwT   = (unsigned short*)(ws + 1 * MB);
  unsigned short* w1T   = (unsigned short*)(ws + 2 * MB);
  unsigned short* w2T   = (unsigned short*)(ws + 4 * MB);
  float*          rowstat = (float*)(ws + 6 * MB);          // 512KB (mu,sigma per row)
  float*          zinv  = (float*)(ws + 7 * MB);            // 256KB max
  unsigned short* xn    = (unsigned short*)(ws + 8 * MB);   // 64MB; reused as h
  char* region = ws + 72 * MB;

  // fused weight prep (1 kernel)
  k_prep<<<1728, 256, 0, stream>>>(mb, gate_w, w1, w2, mb_bf, mbT, gwT, w1T, w2T);
  // LN1 -> xn (bf16) + per-row (mu, sigma)
  k_ln4<<<NTOK / 4, 256, 0, stream>>>(x, ln1g, ln1b, (unsigned*)xn, rowstat);

  if (ws_size >= 264 * MB){
    // ===== PATH A: single chunk S=65536 =====
    const int S = 65536;
    // bigws tier: f1 full-width [region, region+256MB); x2b at +256MB (disjoint).
    const bool bigws = (ws_size >= 400 * MB);
    unsigned short* loc_c = (unsigned short*)(region);                       // 64MB
    unsigned short* ctx_c = (unsigned short*)(region + (size_t)S * 1024);    // 64MB
    unsigned short* sco_c = (unsigned short*)(region + (size_t)S * 2048);    // 64MB
    unsigned short* x2b = bigws ? (unsigned short*)(region + 256 * MB) : sco_c;
    unsigned short* f1  = (unsigned short*)(region);   // 128MB (half) or 256MB (full)

    k_conv8<<<S / 8, 256, 0, stream>>>((const unsigned*)xn, conv_w, conv_b,
                                       (unsigned*)loc_c, 0);
    // e = exp(xn @ mb^T)  (bf16, unnormalized)
    k_g256<2, 512, 512><<<dim3(2, S / 256), 512, 0, stream>>>(xn, mb_bf, sco_c,
                                                              nullptr, nullptr);
    k_rowsum<<<S / 4, 256, 0, stream>>>((const unsigned*)sco_c, zinv);
    // ctx = (e @ mb) * zinv[row]  (bf16)
    k_g256<7, 512, 512><<<dim3(2, S / 256), 512, 0, stream>>>(sco_c, mbT, ctx_c,
                                                              zinv, nullptr);
    // gates+combine (x reconstructed from xn) -> x2 (bf16)
    k_gc256<1><<<dim3(4, S / 256), 512, 0, stream>>>(xn, gwT, gate_b,
                                                     loc_c, ctx_c,
                                                     rowstat, ln1g, ln1b, (void*)x2b);
    // LN2 from bf16 x2
    k_ln4b<<<NTOK / 4, 256, 0, stream>>>((const unsigned*)x2b, ln2g, ln2b, (unsigned*)xn);
    const int S2  = bigws ? S : S / 2;
    const int NC2 = S / S2;
    for (int c = 0; c < NC2; c++){
      const int base = c * S2;
      k_g256<3, 512, 2048><<<dim3(8, S2 / 256), 512, 0, stream>>>(xn + (size_t)base * 512,
                                                                  w1T, f1, b1, nullptr);
      // out = x2(bf16) + f1 @ w2 + b2 -> f32 d_out
      k_g256<5, 2048, 512><<<dim3(2, S2 / 256), 512, 0, stream>>>(f1, w2T,
                                                                  (float*)d_out + (size_t)base * 512,
                                                                  b2,
                                                                  (const void*)(x2b + (size_t)base * 512));
    }
  } else {
    // ===== PATH B: chunked (x2 f32 in d_out) + fused softmax + x-reconstruct =====
    int S = (ws_size >= 120 * MB) ? 16384 : 4096;
    const int S2 = S / 2;
    const int NC  = NTOK / S;
    const int NC2 = NTOK / S2;
    unsigned short* loc_c = (unsigned short*)(region);
    unsigned short* ctx_c = (unsigned short*)(region + (size_t)S * 1024);
    unsigned short* sco_c = (unsigned short*)(region + (size_t)S * 2048);
    unsigned short* f1    = (unsigned short*)(region);

    for (int c = 0; c < NC; c++){
      const int base = c * S;
      const unsigned short* xnc = xn + (size_t)base * 512;
      k_conv8<<<S / 8, 256, 0, stream>>>((const unsigned*)xn, conv_w, conv_b,
                                         (unsigned*)loc_c, base);
      k_g256<2, 512, 512><<<dim3(2, S / 256), 512, 0, stream>>>(xnc, mb_bf, sco_c,
                                                                nullptr, nullptr);
      k_rowsum<<<S / 4, 256, 0, stream>>>((const unsigned*)sco_c, zinv);
      k_g256<7, 512, 512><<<dim3(2, S / 256), 512, 0, stream>>>(sco_c, mbT, ctx_c,
                                                                zinv, nullptr);
      k_gc256<0><<<dim3(4, S / 256), 512, 0, stream>>>(xnc, gwT, gate_b,
                                                       loc_c, ctx_c,
                                                       rowstat + 2 * (size_t)base, ln1g, ln1b,
                                                       (void*)((float*)d_out + (size_t)base * 512));
    }
    k_ln4<<<NTOK / 4, 256, 0, stream>>>((const float*)d_out, ln2g, ln2b, (unsigned*)xn, rowstat);
    for (int c = 0; c < NC2; c++){
      const int base = c * S2;
      k_g256<3, 512, 2048><<<dim3(8, S2 / 256), 512, 0, stream>>>(xn + (size_t)base * 512,
                                                                  w1T, f1, b1, nullptr);
      k_g256<4, 2048, 512><<<dim3(2, S2 / 256), 512, 0, stream>>>(f1, w2T,
                                                                  (float*)d_out + (size_t)base * 512,
                                                                  b2,
                                                                  (const void*)((const float*)d_out + (size_t)base * 512));
    }
  }
}

// Round 21
// 734.665 us; speedup vs baseline: 1.0150x; 1.0150x over previous
//
#include <hip/hip_runtime.h>
#include <math.h>

#define NTOK 65536   // B*T = 8*8192
#define T_   8192
#define C_   512

typedef short short8 __attribute__((ext_vector_type(8)));
typedef float f32x4  __attribute__((ext_vector_type(4)));

#define GLDS(gp, lp) __builtin_amdgcn_global_load_lds( \
    (__attribute__((address_space(1))) void*)(void*)(gp), \
    (__attribute__((address_space(3))) void*)(lp), 16, 0, 0)

__device__ __forceinline__ unsigned short f2bf(float f){
  unsigned x = __float_as_uint(f);
  x += 0x7fffu + ((x >> 16) & 1u);
  return (unsigned short)(x >> 16);
}
__device__ __forceinline__ float bflo(unsigned p){ return __uint_as_float(p << 16); }
__device__ __forceinline__ float bfhi(unsigned p){ return __uint_as_float(p & 0xffff0000u); }
__device__ __forceinline__ float bfs(unsigned short u){ return __uint_as_float(((unsigned)u) << 16); }
__device__ __forceinline__ unsigned pack2(float a, float b){
  return (unsigned)f2bf(a) | ((unsigned)f2bf(b) << 16);
}
// bijective XCD chunking (m204)
__device__ __forceinline__ int xcd_remap(int flat, int nwg){
  int q = nwg >> 3, r = nwg & 7;
  int xcd = flat & 7, idx = flat >> 3;
  return (xcd < r ? xcd * (q + 1) : r * (q + 1) + (xcd - r) * q) + idx;
}

// ---------------- fused weight prep: 1 kernel, block-range dispatch ----------------
__global__ __launch_bounds__(256) void k_prep(const float* __restrict__ mb,
                                              const float* __restrict__ gate_w,
                                              const float* __restrict__ w1,
                                              const float* __restrict__ w2,
                                              unsigned short* __restrict__ mb_bf,
                                              unsigned short* __restrict__ mbT,
                                              unsigned short* __restrict__ gwT,
                                              unsigned short* __restrict__ w1T,
                                              unsigned short* __restrict__ w2T){
  __shared__ float tile[64][65];
  const int bid = blockIdx.x;
  const float* src; unsigned short* dst; int R, S, t0;
  if (bid < 64)       { src = mb;     dst = mbT; R = 512;  S = 512;  t0 = bid; }
  else if (bid < 192) { src = gate_w; dst = gwT; R = 512;  S = 1024; t0 = bid - 64; }
  else if (bid < 448) { src = w1;     dst = w1T; R = 512;  S = 2048; t0 = bid - 192; }
  else if (bid < 704) { src = w2;     dst = w2T; R = 2048; S = 512;  t0 = bid - 448; }
  else {
    int i = (bid - 704) * 256 + threadIdx.x;
    mb_bf[i] = f2bf(mb[i]);
    return;
  }
  int ntS = S >> 6;
  int tr = t0 / ntS, ts = t0 - tr * ntS;
  int tx = threadIdx.x & 63, tg = threadIdx.x >> 6;
  #pragma unroll
  for (int rr = tg; rr < 64; rr += 4)
    tile[rr][tx] = src[(size_t)(tr * 64 + rr) * S + ts * 64 + tx];
  __syncthreads();
  #pragma unroll
  for (int rr = tg; rr < 64; rr += 4)
    dst[(size_t)(ts * 64 + rr) * R + tr * 64 + tx] = f2bf(tile[tx][rr]);
}

// -------- layernorm (f32 in): one row per WAVE; also emits (mu, sigma) per row --------
__global__ __launch_bounds__(256) void k_ln4(const float* __restrict__ x,
                                             const float* __restrict__ g,
                                             const float* __restrict__ b,
                                             unsigned* __restrict__ outbf,
                                             float* __restrict__ rowstat){
  const int row  = blockIdx.x * 4 + (threadIdx.x >> 6);
  const int lane = threadIdx.x & 63;
  const float4* xr = (const float4*)(x + (size_t)row * C_) + lane * 2;
  float4 v0 = xr[0], v1 = xr[1];
  float s  = v0.x + v0.y + v0.z + v0.w + v1.x + v1.y + v1.z + v1.w;
  float ss = v0.x*v0.x + v0.y*v0.y + v0.z*v0.z + v0.w*v0.w
           + v1.x*v1.x + v1.y*v1.y + v1.z*v1.z + v1.w*v1.w;
  #pragma unroll
  for (int o = 32; o; o >>= 1){ s += __shfl_xor(s, o); ss += __shfl_xor(ss, o); }
  float mu  = s * (1.0f / C_);
  float var = ss * (1.0f / C_) - mu * mu;
  float rs = rsqrtf(var + 1e-5f);
  if (lane == 0){ rowstat[2*row] = mu; rowstat[2*row+1] = 1.0f / rs; }
  const float4* gr = (const float4*)g + lane * 2;
  const float4* br = (const float4*)b + lane * 2;
  float4 g0 = gr[0], g1 = gr[1], b0 = br[0], b1 = br[1];
  uint4 o4;
  o4.x = pack2((v0.x - mu) * rs * g0.x + b0.x, (v0.y - mu) * rs * g0.y + b0.y);
  o4.y = pack2((v0.z - mu) * rs * g0.z + b0.z, (v0.w - mu) * rs * g0.w + b0.w);
  o4.z = pack2((v1.x - mu) * rs * g1.x + b1.x, (v1.y - mu) * rs * g1.y + b1.y);
  o4.w = pack2((v1.z - mu) * rs * g1.z + b1.z, (v1.w - mu) * rs * g1.w + b1.w);
  ((uint4*)(outbf + (size_t)row * 256))[lane] = o4;
}

// -------- layernorm (bf16 in): one row per WAVE, shuffle-only reduce --------
__global__ __launch_bounds__(256) void k_ln4b(const unsigned* __restrict__ xb,
                                              const float* __restrict__ g,
                                              const float* __restrict__ b,
                                              unsigned* __restrict__ outbf){
  const int row  = blockIdx.x * 4 + (threadIdx.x >> 6);
  const int lane = threadIdx.x & 63;
  uint4 p = ((const uint4*)(xb + (size_t)row * 256))[lane];
  float v[8];
  v[0]=bflo(p.x); v[1]=bfhi(p.x); v[2]=bflo(p.y); v[3]=bfhi(p.y);
  v[4]=bflo(p.z); v[5]=bfhi(p.z); v[6]=bflo(p.w); v[7]=bfhi(p.w);
  float s = 0.f, ss = 0.f;
  #pragma unroll
  for (int k = 0; k < 8; k++){ s += v[k]; ss += v[k]*v[k]; }
  #pragma unroll
  for (int o = 32; o; o >>= 1){ s += __shfl_xor(s, o); ss += __shfl_xor(ss, o); }
  float mu  = s * (1.0f / C_);
  float var = ss * (1.0f / C_) - mu * mu;
  float rs = rsqrtf(var + 1e-5f);
  const float4* gr = (const float4*)g + lane * 2;
  const float4* br = (const float4*)b + lane * 2;
  float4 g0 = gr[0], g1 = gr[1], b0 = br[0], b1 = br[1];
  uint4 o4;
  o4.x = pack2((v[0] - mu) * rs * g0.x + b0.x, (v[1] - mu) * rs * g0.y + b0.y);
  o4.y = pack2((v[2] - mu) * rs * g0.z + b0.z, (v[3] - mu) * rs * g0.w + b0.w);
  o4.z = pack2((v[4] - mu) * rs * g1.x + b1.x, (v[5] - mu) * rs * g1.y + b1.y);
  o4.w = pack2((v[6] - mu) * rs * g1.z + b1.z, (v[7] - mu) * rs * g1.w + b1.w);
  ((uint4*)(outbf + (size_t)row * 256))[lane] = o4;
}

// ---- depthwise causal conv K=3: 8 consecutive tokens per thread ----
__global__ __launch_bounds__(256) void k_conv8(const unsigned* __restrict__ xn,
                                               const float* __restrict__ w,
                                               const float* __restrict__ bias,
                                               unsigned* __restrict__ loc,
                                               int base){
  const int cp = threadIdx.x;
  const size_t n0 = (size_t)blockIdx.x * 8 + (size_t)base;
  const int t0 = (int)(n0 & (T_ - 1));
  const int c = cp * 2;
  const float w00 = w[c*3], w01 = w[c*3+1], w02 = w[c*3+2];
  const float w10 = w[c*3+3], w11 = w[c*3+4], w12 = w[c*3+5];
  const float b0 = bias[c], b1 = bias[c+1];
  unsigned vm2 = (t0 >= 2) ? xn[(n0 - 2) * 256 + cp] : 0u;
  unsigned vm1 = (t0 >= 1) ? xn[(n0 - 1) * 256 + cp] : 0u;
  size_t obase = (n0 - (size_t)base) * 256 + cp;
  #pragma unroll
  for (int k = 0; k < 8; k++){
    unsigned v = xn[(n0 + k) * 256 + cp];
    float r0 = b0 + bflo(v)*w02 + bflo(vm1)*w01 + bflo(vm2)*w00;
    float r1 = b1 + bfhi(v)*w12 + bfhi(vm1)*w11 + bfhi(vm2)*w10;
    loc[obase + (size_t)k * 256] = pack2(r0, r1);
    vm2 = vm1; vm1 = v;
  }
}

// ---- row sum of exp'd scores (bf16): zinv[row] = 1/sum, one row per wave ----
__global__ __launch_bounds__(256) void k_rowsum(const unsigned* __restrict__ e,
                                                float* __restrict__ zinv){
  const int row  = blockIdx.x * 4 + (threadIdx.x >> 6);
  const int lane = threadIdx.x & 63;
  uint4 p = ((const uint4*)(e + (size_t)row * 256))[lane];
  float s = bflo(p.x)+bfhi(p.x)+bflo(p.y)+bfhi(p.y)
          + bflo(p.z)+bfhi(p.z)+bflo(p.w)+bfhi(p.w);
  #pragma unroll
  for (int o = 32; o; o >>= 1) s += __shfl_xor(s, o);
  if (lane == 0) zinv[row] = 1.0f / s;
}

// =================== 256x256 8-phase bf16 GEMM (T1+T2+T3+T4+T5) — R19-proven ===================
// EPI: 1=bf16, 2=exp(acc)->bf16, 3=gelu(acc+bias)->bf16 (tanh-form via sigmoid),
//      4=acc+bias+f32 add->f32, 5=acc+bias+bf16 add->f32, 7=acc*bias[row]->bf16
#define PH_PRE  { __builtin_amdgcn_s_barrier(); \
                  asm volatile("s_waitcnt lgkmcnt(0)" ::: "memory"); \
                  __builtin_amdgcn_sched_barrier(0); }
#define PH_END  __builtin_amdgcn_s_barrier();
#define VMW2    asm volatile("s_waitcnt vmcnt(2)" ::: "memory");
#define VMW0    asm volatile("s_waitcnt vmcnt(0)" ::: "memory");

template<int EPI, int K, int N>
__global__ __launch_bounds__(512, 2) void k_g256(const unsigned short* __restrict__ A,
                                                 const unsigned short* __restrict__ Bt,
                                                 void* __restrict__ out,
                                                 const float* __restrict__ bias,
                                                 const void* __restrict__ add){
  __shared__ char smem[131072];
  const int tid  = threadIdx.x;
  const int lane = tid & 63;
  const int w    = tid >> 6;
  const int wr   = w >> 2, wc = w & 3;
  const int nwg  = gridDim.x * gridDim.y;
  const int wgid = xcd_remap(blockIdx.y * gridDim.x + blockIdx.x, nwg);
  const long bcol = (long)(wgid % gridDim.x) * 256;
  const long brow = (long)(wgid / gridDim.x) * 256;
  const int lr = lane & 15;
  const int lk = (lane >> 4) * 16;
  const int srow  = tid >> 3;
  const int sbyte = ((tid & 7) * 16) ^ ((srow & 7) << 4);   // T2 pre-swizzled source col
  const unsigned swb = (unsigned)(w * 1024);
  const int rsw = (lr & 7) << 4;                            // T2 read-side XOR

  f32x4 acc[8][4];
  #pragma unroll
  for (int i = 0; i < 8; i++)
    #pragma unroll
    for (int j = 0; j < 4; j++){ f32x4 z = {0.f,0.f,0.f,0.f}; acc[i][j] = z; }

  const char* Ab = (const char*)(A + brow * (long)K);
  const char* Bb = (const char*)(Bt + bcol * (long)K);

  auto ST = [&](const char* g, int ldsoff, int row0, int kt){
    GLDS(g + ((long)(row0 + srow) * K + (long)kt * 64) * 2 + sbyte,
         smem + ldsoff + row0 * 128 + swb);
  };
  auto stA0 = [&](int b, int kt){ ST(Ab, b*32768, 0,  kt); ST(Ab, b*32768, 128, kt); };
  auto stA1 = [&](int b, int kt){ ST(Ab, b*32768, 64, kt); ST(Ab, b*32768, 192, kt); };
  auto stB0 = [&](int b, int kt){ ST(Bb, 65536+b*32768, 0,   kt); ST(Bb, 65536+b*32768, 64,  kt); };
  auto stB1 = [&](int b, int kt){ ST(Bb, 65536+b*32768, 128, kt); ST(Bb, 65536+b*32768, 192, kt); };

  short8 afr[4][2], bfr[2][2];
  auto RDA = [&](int b, int qm){
    #pragma unroll
    for (int mj = 0; mj < 4; mj++)
      #pragma unroll
      for (int kk = 0; kk < 2; kk++)
        afr[mj][kk] = *(const short8*)(smem + b*32768 +
            (wr*128 + (qm*4+mj)*16 + lr) * 128 + ((kk*64 + lk) ^ rsw));
  };
  auto RDB = [&](int b, int qn){
    #pragma unroll
    for (int nj = 0; nj < 2; nj++)
      #pragma unroll
      for (int kk = 0; kk < 2; kk++)
        bfr[nj][kk] = *(const short8*)(smem + 65536 + b*32768 +
            (wc*64 + (qn*2+nj)*16 + lr) * 128 + ((kk*64 + lk) ^ rsw));
  };
  auto MM = [&](int qm, int qn){
    __builtin_amdgcn_s_setprio(1);
    #pragma unroll
    for (int mj = 0; mj < 4; mj++)
      #pragma unroll
      for (int nj = 0; nj < 2; nj++)
        #pragma unroll
        for (int kk = 0; kk < 2; kk++)
          acc[qm*4+mj][qn*2+nj] =
            __builtin_amdgcn_mfma_f32_16x16x32_bf16(afr[mj][kk], bfr[nj][kk],
                                                    acc[qm*4+mj][qn*2+nj], 0, 0, 0);
    __builtin_amdgcn_s_setprio(0);
  };

  constexpr int nt    = K >> 6;
  constexpr int niter = nt >> 1;

  stA0(0, 0); stA1(0, 0); stB0(0, 0); stB1(0, 0);
  stA0(1, 1);
  VMW2;
  __builtin_amdgcn_s_barrier();

  #pragma unroll 1
  for (int i = 0; i < niter; i++){
    const int t = 2 * i;
    RDA(0,0); RDB(0,0); stA1(1, t+1);
    PH_PRE; MM(0,0); PH_END;
    RDA(0,1); stB0(1, t+1);
    PH_PRE; MM(1,0); PH_END;
    RDA(0,0); RDB(0,1); stB1(1, t+1);
    PH_PRE; MM(0,1); PH_END;
    RDA(0,1); if (t + 2 < nt) stA0(0, t+2);
    PH_PRE; MM(1,1);
    if (t + 2 < nt) { VMW2; } else { VMW0; }
    PH_END;
    RDA(1,0); RDB(1,0); if (t + 2 < nt) stA1(0, t+2);
    PH_PRE; MM(0,0); PH_END;
    RDA(1,1); if (t + 2 < nt) stB0(0, t+2);
    PH_PRE; MM(1,0); PH_END;
    RDA(1,0); RDB(1,1); if (t + 2 < nt) stB1(0, t+2);
    PH_PRE; MM(0,1); PH_END;
    RDA(1,1); if (t + 3 < nt) stA0(1, t+3);
    PH_PRE; MM(1,1);
    if (i + 1 < niter){ if (t + 3 < nt) { VMW2; } else { VMW0; } }
    PH_END;
  }

  const long rb = brow + wr * 128;
  const long cb = bcol + wc * 64;
  #pragma unroll
  for (int mi = 0; mi < 8; mi++){
    #pragma unroll
    for (int ni = 0; ni < 4; ni++){
      long rg0 = rb + mi * 16 + (lane >> 4) * 4;
      long cg  = cb + ni * 16 + lr;
      #pragma unroll
      for (int j = 0; j < 4; j++){
        long oi = (rg0 + j) * (long)N + cg;
        float v = acc[mi][ni][j];
        if (EPI == 1){
          ((unsigned short*)out)[oi] = f2bf(v);
        } else if (EPI == 2){
          ((unsigned short*)out)[oi] = f2bf(__expf(v));
        } else if (EPI == 3){
          v += bias[cg];
          // gelu via tanh-form: v * sigmoid(1.59577*(v + 0.044715 v^3))
          float u = v * (1.5957691216f + 0.0713548162f * v * v);
          float gel = v / (1.0f + __expf(-u));
          ((unsigned short*)out)[oi] = f2bf(gel);
        } else if (EPI == 4){
          v += bias[cg] + ((const float*)add)[oi];
          ((float*)out)[oi] = v;
        } else if (EPI == 5){
          v += bias[cg] + bfs(((const unsigned short*)add)[oi]);
          ((float*)out)[oi] = v;
        } else {   // EPI == 7: scale by per-row zinv (softmax normalization)
          v *= bias[rg0 + j];
          ((unsigned short*)out)[oi] = f2bf(v);
        }
      }
    }
  }
}

// ===== fused gates GEMM (8-phase) + sigmoid + gated combine + residual =====
// X2BF: 0 -> write x2 f32, 1 -> write x2 bf16
// x is NOT read: reconstructed from the L2-hot xn panel (A) via per-row (mu,sigma).
template<int X2BF>
__global__ __launch_bounds__(512, 2) void k_gc256(const unsigned short* __restrict__ A,
                                                  const unsigned short* __restrict__ Bt,
                                                  const float* __restrict__ gb,
                                                  const unsigned short* __restrict__ loc,
                                                  const unsigned short* __restrict__ ctx,
                                                  const float* __restrict__ rowstat,
                                                  const float* __restrict__ l1g,
                                                  const float* __restrict__ l1b,
                                                  void* __restrict__ x2v){
  __shared__ char smem[131072];
  const int tid  = threadIdx.x;
  const int lane = tid & 63;
  const int w    = tid >> 6;
  const int wr   = w >> 2, wc = w & 3;
  const int nwg  = gridDim.x * gridDim.y;
  const int wgid = xcd_remap(blockIdx.y * gridDim.x + blockIdx.x, nwg);
  const int  bcol = (wgid % gridDim.x) * 128;
  const long brow = (long)(wgid / gridDim.x) * 256;
  const int K = 512;
  const int lr = lane & 15;
  const int lk = (lane >> 4) * 16;
  const int srow  = tid >> 3;
  const int sbyte = ((tid & 7) * 16) ^ ((srow & 7) << 4);
  const unsigned swb = (unsigned)(w * 1024);
  const int rsw = (lr & 7) << 4;

  f32x4 acc[8][2][2];
  #pragma unroll
  for (int i = 0; i < 8; i++)
    #pragma unroll
    for (int j = 0; j < 2; j++)
      #pragma unroll
      for (int h = 0; h < 2; h++){ f32x4 z = {0.f,0.f,0.f,0.f}; acc[i][j][h] = z; }

  const char* Ab  = (const char*)(A + brow * (long)K);
  const char* BbL = (const char*)(Bt + (long)bcol * K);
  const char* BbG = (const char*)(Bt + (long)(512 + bcol) * K);

  auto ST = [&](const char* g, int ldsoff, int row0, int kt){
    GLDS(g + ((long)(row0 + srow) * K + (long)kt * 64) * 2 + sbyte,
         smem + ldsoff + row0 * 128 + swb);
  };
  auto stA0 = [&](int b, int kt){ ST(Ab, b*32768, 0,  kt); ST(Ab, b*32768, 128, kt); };
  auto stA1 = [&](int b, int kt){ ST(Ab, b*32768, 64, kt); ST(Ab, b*32768, 192, kt); };
  auto stBL = [&](int b, int kt){ ST(BbL, 65536+b*32768,       0, kt); ST(BbL, 65536+b*32768,       64, kt); };
  auto stBG = [&](int b, int kt){ ST(BbG, 65536+b*32768+16384, 0, kt); ST(BbG, 65536+b*32768+16384, 64, kt); };

  short8 afr[4][2], bfr[2][2];
  auto RDA = [&](int b, int qm){
    #pragma unroll
    for (int mj = 0; mj < 4; mj++)
      #pragma unroll
      for (int kk = 0; kk < 2; kk++)
        afr[mj][kk] = *(const short8*)(smem + b*32768 +
            (wr*128 + (qm*4+mj)*16 + lr) * 128 + ((kk*64 + lk) ^ rsw));
  };
  auto RDB = [&](int b, int h){
    #pragma unroll
    for (int nj = 0; nj < 2; nj++)
      #pragma unroll
      for (int kk = 0; kk < 2; kk++)
        bfr[nj][kk] = *(const short8*)(smem + 65536 + b*32768 + h*16384 +
            (wc*32 + nj*16 + lr) * 128 + ((kk*64 + lk) ^ rsw));
  };
  auto MM = [&](int qm, int h){
    __builtin_amdgcn_s_setprio(1);
    #pragma unroll
    for (int mj = 0; mj < 4; mj++)
      #pragma unroll
      for (int nj = 0; nj < 2; nj++)
        #pragma unroll
        for (int kk = 0; kk < 2; kk++)
          acc[qm*4+mj][nj][h] =
            __builtin_amdgcn_mfma_f32_16x16x32_bf16(afr[mj][kk], bfr[nj][kk],
                                                    acc[qm*4+mj][nj][h], 0, 0, 0);
    __builtin_amdgcn_s_setprio(0);
  };

  constexpr int nt = 8, niter = 4;   // K=512

  stA0(0, 0); stA1(0, 0); stBL(0, 0); stBG(0, 0);
  stA0(1, 1);
  VMW2;
  __builtin_amdgcn_s_barrier();

  #pragma unroll 1
  for (int i = 0; i < niter; i++){
    const int t = 2 * i;
    RDA(0,0); RDB(0,0); stA1(1, t+1);
    PH_PRE; MM(0,0); PH_END;
    RDA(0,1); stBL(1, t+1);
    PH_PRE; MM(1,0); PH_END;
    RDA(0,0); RDB(0,1); stBG(1, t+1);
    PH_PRE; MM(0,1); PH_END;
    RDA(0,1); if (t + 2 < nt) stA0(0, t+2);
    PH_PRE; MM(1,1);
    if (t + 2 < nt) { VMW2; } else { VMW0; }
    PH_END;
    RDA(1,0); RDB(1,0); if (t + 2 < nt) stA1(0, t+2);
    PH_PRE; MM(0,0); PH_END;
    RDA(1,1); if (t + 2 < nt) stBL(0, t+2);
    PH_PRE; MM(1,0); PH_END;
    RDA(1,0); RDB(1,1); if (t + 2 < nt) stBG(0, t+2);
    PH_PRE; MM(0,1); PH_END;
    RDA(1,1); if (t + 3 < nt) stA0(1, t+3);
    PH_PRE; MM(1,1);
    if (i + 1 < niter){ if (t + 3 < nt) { VMW2; } else { VMW0; } }
    PH_END;
  }

  const long rbase = brow + wr * 128;
  const int  cb_   = bcol + wc * 32;
  // pass 1: issue xn re-reads (L2-hot: this block just streamed its A-panel)
  unsigned short xnp[8][2][4];
  #pragma unroll
  for (int mi = 0; mi < 8; mi++){
    #pragma unroll
    for (int ni = 0; ni < 2; ni++){
      long rg0 = rbase + mi * 16 + (lane >> 4) * 4;
      int  cg  = cb_ + ni * 16 + lr;
      #pragma unroll
      for (int j = 0; j < 4; j++)
        xnp[mi][ni][j] = A[(rg0 + j) * 512 + cg];
    }
  }
  // pass 2: reconstruct x, sigmoid-combine, store
  #pragma unroll
  for (int mi = 0; mi < 8; mi++){
    #pragma unroll
    for (int ni = 0; ni < 2; ni++){
      long rg0 = rbase + mi * 16 + (lane >> 4) * 4;
      int  cg  = cb_ + ni * 16 + lr;
      float bL = gb[cg], bG = gb[512 + cg];
      float lg = l1g[cg], lb = l1b[cg];
      float ig = 1.0f / lg;
      #pragma unroll
      for (int j = 0; j < 4; j++){
        long rg = rg0 + j;
        long oi = rg * 512 + cg;
        float mu = rowstat[2*rg], sg = rowstat[2*rg+1];
        float xv = (bfs(xnp[mi][ni][j]) - lb) * ig * sg + mu;
        float vL = 1.0f / (1.0f + __expf(-(acc[mi][ni][0][j] + bL)));
        float vG = 1.0f / (1.0f + __expf(-(acc[mi][ni][1][j] + bG)));
        float r = xv + vL * bfs(loc[oi]) + vG * bfs(ctx[oi]);
        if (X2BF) ((unsigned short*)x2v)[oi] = f2bf(r);
        else      ((float*)x2v)[oi] = r;
      }
    }
  }
}

// ---------------- launch ----------------
extern "C" void kernel_launch(void* const* d_in, const int* in_sizes, int n_in,
                              void* d_out, int out_size, void* d_ws, size_t ws_size,
                              hipStream_t stream){
  const float* x      = (const float*)d_in[0];
  const float* conv_w = (const float*)d_in[1];
  const float* conv_b = (const float*)d_in[2];
  const float* mb     = (const float*)d_in[3];
  const float* gate_w = (const float*)d_in[4];
  const float* gate_b = (const float*)d_in[5];
  const float* w1     = (const float*)d_in[6];
  const float* b1     = (const float*)d_in[7];
  const float* w2     = (const float*)d_in[8];
  const float* b2     = (const float*)d_in[9];
  const float* ln1g   = (const float*)d_in[10];
  const float* ln1b   = (const float*)d_in[11];
  const float* ln2g   = (const float*)d_in[12];
  const float* ln2b   = (const float*)d_in[13];

  char* ws = (char*)d_ws;
  const size_t MB = 1024ull * 1024ull;
  unsigned short* mb_bf = (unsigned short*)(ws + 0);
  unsigned short* mbT   = (unsigned short*)(ws + 512 * 1024);
  unsigned short* gwT   = (unsigned short*)(ws + 1 * MB);
  unsigned short* w1T   = (unsigned short*)(ws + 2 * MB);
  unsigned short* w2T   = (unsigned short*)(ws + 4 * MB);
  float*          rowstat = (float*)(ws + 6 * MB);          // 512KB (mu,sigma per row)
  float*          zinv  = (float*)(ws + 7 * MB);            // 256KB max
  unsigned short* xn    = (unsigned short*)(ws + 8 * MB);   // 64MB; reused as h
  char* region = ws + 72 * MB;

  // fused weight prep (1 kernel)
  k_prep<<<1728, 256, 0, stream>>>(mb, gate_w, w1, w2, mb_bf, mbT, gwT, w1T, w2T);
  // LN1 -> xn (bf16) + per-row (mu, sigma)
  k_ln4<<<NTOK / 4, 256, 0, stream>>>(x, ln1g, ln1b, (unsigned*)xn, rowstat);

  if (ws_size >= 264 * MB){
    // ===== PATH A: single chunk S=65536 =====
    const int S = 65536;
    // bigws tier: f1 full-width [region, region+256MB); x2b at +256MB (disjoint).
    const bool bigws = (ws_size >= 400 * MB);
    unsigned short* loc_c = (unsigned short*)(region);                       // 64MB
    unsigned short* ctx_c = (unsigned short*)(region + (size_t)S * 1024);    // 64MB
    unsigned short* sco_c = (unsigned short*)(region + (size_t)S * 2048);    // 64MB
    unsigned short* x2b = bigws ? (unsigned short*)(region + 256 * MB) : sco_c;
    unsigned short* f1  = (unsigned short*)(region);   // 128MB (half) or 256MB (full)

    k_conv8<<<S / 8, 256, 0, stream>>>((const unsigned*)xn, conv_w, conv_b,
                                       (unsigned*)loc_c, 0);
    // e = exp(xn @ mb^T)  (bf16, unnormalized)
    k_g256<2, 512, 512><<<dim3(2, S / 256), 512, 0, stream>>>(xn, mb_bf, sco_c,
                                                              nullptr, nullptr);
    k_rowsum<<<S / 4, 256, 0, stream>>>((const unsigned*)sco_c, zinv);
    // ctx = (e @ mb) * zinv[row]  (bf16)
    k_g256<7, 512, 512><<<dim3(2, S / 256), 512, 0, stream>>>(sco_c, mbT, ctx_c,
                                                              zinv, nullptr);
    // gates+combine (x reconstructed from xn) -> x2 (bf16)
    k_gc256<1><<<dim3(4, S / 256), 512, 0, stream>>>(xn, gwT, gate_b,
                                                     loc_c, ctx_c,
                                                     rowstat, ln1g, ln1b, (void*)x2b);
    // LN2 from bf16 x2
    k_ln4b<<<NTOK / 4, 256, 0, stream>>>((const unsigned*)x2b, ln2g, ln2b, (unsigned*)xn);
    const int S2  = bigws ? S : S / 2;
    const int NC2 = S / S2;
    for (int c = 0; c < NC2; c++){
      const int base = c * S2;
      k_g256<3, 512, 2048><<<dim3(8, S2 / 256), 512, 0, stream>>>(xn + (size_t)base * 512,
                                                                  w1T, f1, b1, nullptr);
      // out = x2(bf16) + f1 @ w2 + b2 -> f32 d_out
      k_g256<5, 2048, 512><<<dim3(2, S2 / 256), 512, 0, stream>>>(f1, w2T,
                                                                  (float*)d_out + (size_t)base * 512,
                                                                  b2,
                                                                  (const void*)(x2b + (size_t)base * 512));
    }
  } else {
    // ===== PATH B: chunked (x2 f32 in d_out) + fused softmax + x-reconstruct =====
    int S = (ws_size >= 120 * MB) ? 16384 : 4096;
    const int S2 = S / 2;
    const int NC  = NTOK / S;
    const int NC2 = NTOK / S2;
    unsigned short* loc_c = (unsigned short*)(region);
    unsigned short* ctx_c = (unsigned short*)(region + (size_t)S * 1024);
    unsigned short* sco_c = (unsigned short*)(region + (size_t)S * 2048);
    unsigned short* f1    = (unsigned short*)(region);

    for (int c = 0; c < NC; c++){
      const int base = c * S;
      const unsigned short* xnc = xn + (size_t)base * 512;
      k_conv8<<<S / 8, 256, 0, stream>>>((const unsigned*)xn, conv_w, conv_b,
                                         (unsigned*)loc_c, base);
      k_g256<2, 512, 512><<<dim3(2, S / 256), 512, 0, stream>>>(xnc, mb_bf, sco_c,
                                                                nullptr, nullptr);
      k_rowsum<<<S / 4, 256, 0, stream>>>((const unsigned*)sco_c, zinv);
      k_g256<7, 512, 512><<<dim3(2, S / 256), 512, 0, stream>>>(sco_c, mbT, ctx_c,
                                                                zinv, nullptr);
      k_gc256<0><<<dim3(4, S / 256), 512, 0, stream>>>(xnc, gwT, gate_b,
                                                       loc_c, ctx_c,
                                                       rowstat + 2 * (size_t)base, ln1g, ln1b,
                                                       (void*)((float*)d_out + (size_t)base * 512));
    }
    k_ln4<<<NTOK / 4, 256, 0, stream>>>((const float*)d_out, ln2g, ln2b, (unsigned*)xn, rowstat);
    for (int c = 0; c < NC2; c++){
      const int base = c * S2;
      k_g256<3, 512, 2048><<<dim3(8, S2 / 256), 512, 0, stream>>>(xn + (size_t)base * 512,
                                                                  w1T, f1, b1, nullptr);
      k_g256<4, 2048, 512><<<dim3(2, S2 / 256), 512, 0, stream>>>(f1, w2T,
                                                                  (float*)d_out + (size_t)base * 512,
                                                                  b2,
                                                                  (const void*)((const float*)d_out + (size_t)base * 512));
    }
  }
}